// Round 12
// baseline (101.496 us; speedup 1.0000x reference)
//
#include <hip/hip_runtime.h>
#include <hip/hip_bf16.h>
#include <stdint.h>

#define B_  2
#define NF_ 2048
#define NE_ 4096
#define FD_ 128
#define HD_ 64
#define H_  4

#define LOG2E 1.44269504f
#define KH    8.65617025f   // (12 * log2e) / 2

typedef unsigned long long u64;
typedef __attribute__((ext_vector_type(2))) float f32x2;
typedef __attribute__((ext_vector_type(4))) float f32x4;
typedef __attribute__((ext_vector_type(8))) short bf16x8;

__device__ __forceinline__ float wave_sum64(float v) {
  #pragma unroll
  for (int m = 32; m >= 1; m >>= 1) v += __shfl_xor(v, m, 64);
  return v;
}
__device__ __forceinline__ float wave_max64(float v) {
  #pragma unroll
  for (int m = 32; m >= 1; m >>= 1) v = fmaxf(v, __shfl_xor(v, m, 64));
  return v;
}
__device__ __forceinline__ unsigned short bf16rne(float x) {
  unsigned u = __float_as_uint(x);
  return (unsigned short)((u + 0x7FFFu + ((u >> 16) & 1u)) >> 16);
}

// ---- pre: tile W into A-fragment bf16 layout + Wa = (W @ a) * log2e ----
__global__ __launch_bounds__(256) void pre_kernel(
    const float* __restrict__ Wf, const float* __restrict__ We,
    const float* __restrict__ a_fe, const float* __restrict__ a_ef,
    __hip_bfloat16* __restrict__ Wfrag, float* __restrict__ Wa)
{
  const int lane = threadIdx.x & 63, wid = threadIdx.x >> 6;
  const int dir = blockIdx.x >> 2, h = blockIdx.x & 3;
  const int cl = lane & 15, kq = lane >> 4;
  const float* W = (dir ? We : Wf) + (size_t)h * FD_ * HD_;
  __hip_bfloat16* fb = Wfrag + (size_t)(dir * 4 + h) * 8192;
  #pragma unroll
  for (int db = 0; db < 4; ++db) {
    unsigned short u[8];
    #pragma unroll
    for (int j = 0; j < 8; ++j)
      u[j] = bf16rne(W[(wid * 32 + kq * 8 + j) * HD_ + db * 16 + cl]);
    uint4 pk;
    pk.x = u[0] | ((unsigned)u[1] << 16);
    pk.y = u[2] | ((unsigned)u[3] << 16);
    pk.z = u[4] | ((unsigned)u[5] << 16);
    pk.w = u[6] | ((unsigned)u[7] << 16);
    *(uint4*)(fb + ((size_t)(wid * 4 + db) * 64 + lane) * 8) = pk;
  }
  if (wid == 0) {
    const float* a1 = a_fe + h * HD_;
    const float* a2 = a_ef + h * HD_;
    float* wa = Wa + (size_t)(dir * 4 + h) * 256;
    #pragma unroll
    for (int rep = 0; rep < 2; ++rep) {
      const int f = lane + rep * 64;
      const float* wr = W + (size_t)f * HD_;
      float s1 = 0.f, s2 = 0.f;
      #pragma unroll 8
      for (int d = 0; d < HD_; ++d) {
        s1 = fmaf(wr[d], a1[d], s1);
        s2 = fmaf(wr[d], a2[d], s2);
      }
      wa[f] = s1 * LOG2E;
      wa[128 + f] = s2 * LOG2E;
    }
  }
}

// ---- MFMA proj: 16 rows/wave; fragment-tiled V + row float2 + col f32 E/G ----
template<int SWAP, int NN>
__device__ __forceinline__ void proj_mfma(
    const float* __restrict__ X0, const __hip_bfloat16* __restrict__ Wfrag,
    const float* __restrict__ Wa, __hip_bfloat16* __restrict__ Vp,
    float2* __restrict__ rowO, float* __restrict__ colEO,
    float* __restrict__ colGO, int job, float* __restrict__ ldsX)
{
  const int lane = threadIdx.x & 63;
  const int cl = lane & 15, kq = lane >> 4;
  const int nj = NN >> 4;
  const int nt = job & (nj - 1);
  const int bh = job / nj;
  const int n0 = nt * 16;
  const int h = bh & 3, b = bh >> 2;
  const float* x0 = X0 + ((size_t)b * NN + n0 + cl) * FD_ + kq * 8;
  const __hip_bfloat16* fb = Wfrag + (size_t)((SWAP ? 4 : 0) + h) * 8192;
  const float* wa = Wa + (size_t)((SWAP ? 4 : 0) + h) * 256 + kq * 8;

  bf16x8 wf[4][4];
  #pragma unroll
  for (int ks = 0; ks < 4; ++ks)
    #pragma unroll
    for (int db = 0; db < 4; ++db)
      wf[ks][db] = *(const bf16x8*)(fb + ((size_t)(ks * 4 + db) * 64 + lane) * 8);

  bf16x8 xf[4];
  float d1 = 0.f, d2 = 0.f;
  #pragma unroll
  for (int ks = 0; ks < 4; ++ks) {
    const f32x4 xa = *(const f32x4*)(x0 + ks * 32);
    const f32x4 xb = *(const f32x4*)(x0 + ks * 32 + 4);
    const f32x4 w1a = *(const f32x4*)(wa + ks * 32);
    const f32x4 w1b = *(const f32x4*)(wa + ks * 32 + 4);
    const f32x4 w2a = *(const f32x4*)(wa + 128 + ks * 32);
    const f32x4 w2b = *(const f32x4*)(wa + 128 + ks * 32 + 4);
    #pragma unroll
    for (int i = 0; i < 4; ++i) {
      d1 = fmaf(xa[i], w1a[i], fmaf(xb[i], w1b[i], d1));
      d2 = fmaf(xa[i], w2a[i], fmaf(xb[i], w2b[i], d2));
    }
    #pragma unroll
    for (int i = 0; i < 4; ++i) {
      xf[ks][i]     = (short)bf16rne(xa[i]);
      xf[ks][i + 4] = (short)bf16rne(xb[i]);
    }
  }
  d1 += __shfl_xor(d1, 16, 64); d1 += __shfl_xor(d1, 32, 64);
  d2 += __shfl_xor(d2, 16, 64); d2 += __shfl_xor(d2, 32, 64);

  f32x4 acc[4] = {};
  #pragma unroll
  for (int ks = 0; ks < 4; ++ks)
    #pragma unroll
    for (int db = 0; db < 4; ++db)
      acc[db] = __builtin_amdgcn_mfma_f32_16x16x32_bf16(wf[ks][db], xf[ks],
                                                        acc[db], 0, 0, 0);
  #pragma unroll
  for (int db = 0; db < 4; ++db)
    *(f32x4*)(ldsX + cl * 68 + db * 16 + kq * 4) = acc[db];
  const int mt = n0 >> 6;
  #pragma unroll
  for (int c = 0; c < 2; ++c) {
    const int nb = n0 + c * 8;
    const int ks2 = (nb >> 5) & 1, q2 = (nb >> 3) & 3;
    unsigned short u[8];
    #pragma unroll
    for (int j = 0; j < 8; ++j)
      u[j] = bf16rne(ldsX[(c * 8 + j) * 68 + lane]);
    uint4 pk;
    pk.x = u[0] | ((unsigned)u[1] << 16);
    pk.y = u[2] | ((unsigned)u[3] << 16);
    pk.z = u[4] | ((unsigned)u[5] << 16);
    pk.w = u[6] | ((unsigned)u[7] << 16);
    *(uint4*)(Vp + ((size_t)((mt * 8 + ks2 * 4 + (lane >> 4)) * 64
                             + q2 * 16 + (lane & 15))) * 8) = pk;
  }
  if (kq == 0) {
    const float rd = SWAP ? d2 : d1;
    const float cd = SWAP ? d1 : d2;
    float2 rp;
    rp.x = exp2f(rd - KH);
    rp.y = exp2f(0.2f * rd - KH);
    const size_t idxn = (size_t)bh * NN + n0 + cl;
    rowO[idxn] = rp;
    colEO[idxn] = exp2f(cd - KH);
    colGO[idxn] = exp2f(0.2f * cd - KH);
  }
}

// ---- bitpack: transposed bits_t[mt][n] ----
__device__ __forceinline__ void bitpack_body(
    const int* __restrict__ adj_fe, const int* __restrict__ adj_ef,
    u64* __restrict__ btfe, u64* __restrict__ btef, int id)
{
  const int lane = threadIdx.x & 63;
  const int* adj; u64* bt; int N, M, mt, g;
  if (id < 8192) {                            // fe: 64 mt x 128 g
    adj = adj_fe; bt = btfe; N = NF_; M = NE_;
    mt = id >> 7; g = id & 127;
  } else {                                    // ef: 32 mt x 256 g
    const int k = id - 8192;
    adj = adj_ef; bt = btef; N = NE_; M = NF_;
    mt = k >> 8; g = k & 255;
  }
  const int* base = adj + (size_t)(g * 16) * M + mt * 64 + lane;
  int v[16];
  #pragma unroll
  for (int r = 0; r < 16; ++r) v[r] = base[(size_t)r * M];
  u64 mine = 0;
  #pragma unroll
  for (int r = 0; r < 16; ++r) {
    u64 msk = __ballot(v[r] != 0);
    if (lane == r) mine = msk;
  }
  if (lane < 16) bt[(size_t)mt * N + g * 16 + lane] = mine;
}

// ---- fused prep ----
__global__ __launch_bounds__(256) void prep_kernel(
    const float* __restrict__ F0, const float* __restrict__ E0,
    const int* __restrict__ adj_fe, const int* __restrict__ adj_ef,
    const __hip_bfloat16* __restrict__ Wfrag, const float* __restrict__ Wa,
    __hip_bfloat16* __restrict__ Ftl, __hip_bfloat16* __restrict__ Etl,
    float2* __restrict__ rowF, float* __restrict__ colEF, float* __restrict__ colGF,
    float2* __restrict__ rowE, float* __restrict__ colEE, float* __restrict__ colGE,
    u64* __restrict__ btfe, u64* __restrict__ btef)
{
  __shared__ __align__(16) float ldsX[4][16 * 68];
  const int blk = blockIdx.x;
  const int wid = threadIdx.x >> 6;
  if (blk < 4096) {
    bitpack_body(adj_fe, adj_ef, btfe, btef, blk * 4 + wid);
  } else {
    const int job = (blk - 4096) * 4 + wid;   // [0, 3072)
    if (job < 1024) {
      const int bh = job >> 7;
      proj_mfma<0, NF_>(F0, Wfrag, Wa, Ftl + (size_t)bh * 32 * 4096,
                        rowF, colEF, colGF, job, ldsX[wid]);
    } else {
      const int j2 = job - 1024;
      const int bh = j2 >> 8;
      proj_mfma<1, NE_>(E0, Wfrag, Wa, Etl + (size_t)bh * 64 * 4096,
                        rowE, colEE, colGE, j2, ldsX[wid]);
    }
  }
}

// ---- attention inner loop: 1 fragment; packed-f32 P build.
// P pair: v_pk_mul x2 + v_pk_max + sbfe/and mask + cvt_pk -> ~4 VALU/elem.
template<int TQ, int NN>
__device__ __forceinline__ void attn_wave(
    const __hip_bfloat16* __restrict__ vpp, const float* __restrict__ colE,
    const float* __restrict__ colG, const u64* __restrict__ bt,
    float Ea, float Ga, int n0, int mt0, int cl, int kq,
    f32x4 (&accT)[4], f32x4 &accS)
{
  const int lane = threadIdx.x & 63;
  bf16x8 ones;
  #pragma unroll
  for (int i = 0; i < 8; ++i) ones[i] = (short)0x3F80;  // bf16 1.0

  const __hip_bfloat16* tb = vpp + (size_t)mt0 * 4096 + (size_t)lane * 8;
  const float* ce = colE + mt0 * 64 + kq * 8;
  const float* cg = colG + mt0 * 64 + kq * 8;
  const u64* bp = bt + (size_t)mt0 * NN + n0 + cl;
  const int shk = kq * 8;
  const f32x2 EaP = {Ea, Ea}, GaP = {Ga, Ga};

  #pragma unroll 1
  for (int t = 0; t < TQ; ++t) {
    const bf16x8 vf0 = *(const bf16x8*)(tb);
    const bf16x8 vf1 = *(const bf16x8*)(tb + 512);
    const bf16x8 vf2 = *(const bf16x8*)(tb + 1024);
    const bf16x8 vf3 = *(const bf16x8*)(tb + 1536);
    const bf16x8 vf4 = *(const bf16x8*)(tb + 2048);
    const bf16x8 vf5 = *(const bf16x8*)(tb + 2560);
    const bf16x8 vf6 = *(const bf16x8*)(tb + 3072);
    const bf16x8 vf7 = *(const bf16x8*)(tb + 3584);
    const f32x4 ea0 = *(const f32x4*)(ce);
    const f32x4 ea1 = *(const f32x4*)(ce + 4);
    const f32x4 ea2 = *(const f32x4*)(ce + 32);
    const f32x4 ea3 = *(const f32x4*)(ce + 36);
    const f32x4 ga0 = *(const f32x4*)(cg);
    const f32x4 ga1 = *(const f32x4*)(cg + 4);
    const f32x4 ga2 = *(const f32x4*)(cg + 32);
    const f32x4 ga3 = *(const f32x4*)(cg + 36);
    const u64 s0 = (*bp) >> shk;
    tb += 4096; ce += 64; cg += 64; bp += NN;

    bf16x8 pf;
    unsigned mw;

#define PP(EV, GV, I, J) {                                                \
      const f32x2 pe = EaP * (f32x2){(EV)[I], (EV)[(I) + 1]};             \
      const f32x2 pg = GaP * (f32x2){(GV)[I], (GV)[(I) + 1]};             \
      f32x2 pm = __builtin_elementwise_max(pe, pg);                       \
      const int m0 = __builtin_amdgcn_sbfe((int)mw, (J), 1);              \
      const int m1 = __builtin_amdgcn_sbfe((int)mw, (J) + 1, 1);          \
      __hip_bfloat16 h0 =                                                 \
          __float2bfloat16(__int_as_float(__float_as_int(pm.x) & m0));    \
      __hip_bfloat16 h1 =                                                 \
          __float2bfloat16(__int_as_float(__float_as_int(pm.y) & m1));    \
      pf[(J)]     = *(const short*)&h0;                                   \
      pf[(J) + 1] = *(const short*)&h1;                                   \
    }

    // ---- ks = 0 ----
    mw = (unsigned)s0;
    PP(ea0, ga0, 0, 0) PP(ea0, ga0, 2, 2) PP(ea1, ga1, 0, 4) PP(ea1, ga1, 2, 6)
    accS = __builtin_amdgcn_mfma_f32_16x16x32_bf16(pf, ones, accS, 0, 0, 0);
    accT[0] = __builtin_amdgcn_mfma_f32_16x16x32_bf16(pf, vf0, accT[0], 0, 0, 0);
    accT[1] = __builtin_amdgcn_mfma_f32_16x16x32_bf16(pf, vf1, accT[1], 0, 0, 0);
    accT[2] = __builtin_amdgcn_mfma_f32_16x16x32_bf16(pf, vf2, accT[2], 0, 0, 0);
    accT[3] = __builtin_amdgcn_mfma_f32_16x16x32_bf16(pf, vf3, accT[3], 0, 0, 0);

    // ---- ks = 1 ----
    mw = (unsigned)(s0 >> 32);
    PP(ea2, ga2, 0, 0) PP(ea2, ga2, 2, 2) PP(ea3, ga3, 0, 4) PP(ea3, ga3, 2, 6)
    accS = __builtin_amdgcn_mfma_f32_16x16x32_bf16(pf, ones, accS, 0, 0, 0);
    accT[0] = __builtin_amdgcn_mfma_f32_16x16x32_bf16(pf, vf4, accT[0], 0, 0, 0);
    accT[1] = __builtin_amdgcn_mfma_f32_16x16x32_bf16(pf, vf5, accT[1], 0, 0, 0);
    accT[2] = __builtin_amdgcn_mfma_f32_16x16x32_bf16(pf, vf6, accT[2], 0, 0, 0);
    accT[3] = __builtin_amdgcn_mfma_f32_16x16x32_bf16(pf, vf7, accT[3], 0, 0, 0);
#undef PP
  }
}

// ---- fused attention: block = 16 rows, 4 waves split M; XCD-local bh ----
__global__ __launch_bounds__(256) void attn_kernel(
    const __hip_bfloat16* __restrict__ Ftl, const __hip_bfloat16* __restrict__ Etl,
    const float2* __restrict__ rowF, const float* __restrict__ colEF,
    const float* __restrict__ colGF, const float2* __restrict__ rowE,
    const float* __restrict__ colEE, const float* __restrict__ colGE,
    const u64* __restrict__ btfe, const u64* __restrict__ btef,
    float* __restrict__ out)
{
  __shared__ __align__(16) float ldsO[4 * 4 * 64 * 4];  // 16KB
  __shared__ float ldsS[4 * 16];

  const int lane = threadIdx.x & 63;
  const int wid  = threadIdx.x >> 6;
  const int cl = lane & 15, kq = lane >> 4;
  const int blk = blockIdx.x;

  int N, bh, n0;
  float* obase;
  bool relu;
  f32x4 accT[4] = {};
  f32x4 accS = {0.f, 0.f, 0.f, 0.f};

  if (blk < 1024) {            // fe
    bh = blk & 7;
    n0 = (blk >> 3) * 16;
    N = NF_;
    const float2 rp = rowF[(size_t)bh * NF_ + n0 + cl];
    attn_wave<16, NF_>(Etl + (size_t)bh * 64 * 4096,
                       colEE + (size_t)bh * NE_, colGE + (size_t)bh * NE_,
                       btfe, rp.x, rp.y, n0, wid * 16, cl, kq, accT, accS);
    obase = out; relu = false;
  } else {                     // ef
    const int k2 = blk - 1024;
    bh = k2 & 7;
    n0 = (k2 >> 3) * 16;
    N = NE_;
    const float2 rp = rowE[(size_t)bh * NE_ + n0 + cl];
    attn_wave<8, NE_>(Ftl + (size_t)bh * 32 * 4096,
                      colEF + (size_t)bh * NF_, colGF + (size_t)bh * NF_,
                      btef, rp.x, rp.y, n0, wid * 8, cl, kq, accT, accS);
    obase = out + (size_t)B_ * NF_ * 256; relu = true;
  }

  #pragma unroll
  for (int db = 0; db < 4; ++db)
    *(f32x4*)&ldsO[((db * 4 + wid) * 64 + lane) * 4] = accT[db];
  if (cl == 0) {
    #pragma unroll
    for (int reg = 0; reg < 4; ++reg)
      ldsS[wid * 16 + kq * 4 + reg] = accS[reg];
  }
  __syncthreads();

  f32x4 osum = {0.f, 0.f, 0.f, 0.f};
  #pragma unroll
  for (int s = 0; s < 4; ++s)
    osum += *(const f32x4*)&ldsO[((wid * 4 + s) * 64 + lane) * 4];
  float stot[4];
  #pragma unroll
  for (int reg = 0; reg < 4; ++reg) {
    stot[reg] = 0.f;
    #pragma unroll
    for (int s = 0; s < 4; ++s) stot[reg] += ldsS[s * 16 + kq * 4 + reg];
  }
  const int b = bh >> 2, h = bh & 3;
  float* orow = obase + ((size_t)b * N + n0 + kq * 4) * 256 + h * HD_ + wid * 16 + cl;
  #pragma unroll
  for (int reg = 0; reg < 4; ++reg) {
    float v = osum[reg] / stot[reg];
    if (relu) v = fmaxf(v, 0.0f);
    orow[reg * 256] = v;
  }
}

// in-place softmax over the 256-channel axis
__global__ __launch_bounds__(256) void softmax256_kernel(float* __restrict__ io)
{
  const int t = threadIdx.x;
  const int lane = t & 63, wid = t >> 6;
  float v = io[(long)blockIdx.x * 256 + t];
  __shared__ float red[8];
  float m = wave_max64(v);
  if (lane == 0) red[wid] = m;
  __syncthreads();
  m = fmaxf(fmaxf(red[0], red[1]), fmaxf(red[2], red[3]));
  float e = __expf(v - m);
  float s = wave_sum64(e);
  if (lane == 0) red[4 + wid] = s;
  __syncthreads();
  s = (red[4] + red[5]) + (red[6] + red[7]);
  io[(long)blockIdx.x * 256 + t] = e / s;
}

extern "C" void kernel_launch(void* const* d_in, const int* in_sizes, int n_in,
                              void* d_out, int out_size, void* d_ws, size_t ws_size,
                              hipStream_t stream)
{
  const float* F0   = (const float*)d_in[0];
  const float* E0   = (const float*)d_in[1];
  const int* adj_fe = (const int*)d_in[2];
  const int* adj_ef = (const int*)d_in[3];
  const float* Wf   = (const float*)d_in[4];
  const float* We   = (const float*)d_in[5];
  const float* a_fe = (const float*)d_in[6];
  const float* a_ef = (const float*)d_in[7];
  float* out = (float*)d_out;

  char* ws = (char*)d_ws;
  float2* rowF = (float2*)ws;                         // 16384 * 8B = 128KB
  float2* rowE = (float2*)(ws + (128 << 10));         // 32768 * 8B = 256KB
  float* colEF = (float*)(ws + (384 << 10));          // 16384 * 4B = 64KB
  float* colGF = (float*)(ws + (448 << 10));          // 64KB
  float* colEE = (float*)(ws + (512 << 10));          // 32768 * 4B = 128KB
  float* colGE = (float*)(ws + (640 << 10));          // 128KB
  u64* btfe = (u64*)(ws + (768 << 10));               // 1MB
  u64* btef = btfe + (size_t)NF_ * (NE_ / 64);        // 1MB
  __hip_bfloat16* Ftl = (__hip_bfloat16*)(btef + (size_t)NE_ * (NF_ / 64)); // 2MB
  __hip_bfloat16* Etl = Ftl + (size_t)8 * 32 * 4096;  // 4MB
  __hip_bfloat16* Wfrag = Etl + (size_t)8 * 64 * 4096;
  float* Wa = (float*)(Wfrag + (size_t)8 * 8192);

  pre_kernel<<<8, 256, 0, stream>>>(Wf, We, a_fe, a_ef, Wfrag, Wa);
  prep_kernel<<<4864, 256, 0, stream>>>(F0, E0, adj_fe, adj_ef, Wfrag, Wa,
                                        Ftl, Etl, rowF, colEF, colGF,
                                        rowE, colEE, colGE, btfe, btef);
  attn_kernel<<<3072, 256, 0, stream>>>(Ftl, Etl, rowF, colEF, colGF,
                                        rowE, colEE, colGE, btfe, btef, out);
  softmax256_kernel<<<B_ * NF_, 256, 0, stream>>>(out);
}

// Round 13
// 91.116 us; speedup vs baseline: 1.1139x; 1.1139x over previous
//
#include <hip/hip_runtime.h>
#include <hip/hip_bf16.h>
#include <stdint.h>

#define B_  2
#define NF_ 2048
#define NE_ 4096
#define FD_ 128
#define HD_ 64
#define H_  4

#define LOG2E 1.44269504f
#define KH    8.65617025f   // (12 * log2e) / 2

typedef unsigned long long u64;
typedef __attribute__((ext_vector_type(4))) float f32x4;
typedef __attribute__((ext_vector_type(8))) short bf16x8;
typedef __attribute__((ext_vector_type(4))) unsigned uint32x4;

__device__ __forceinline__ float wave_sum64(float v) {
  #pragma unroll
  for (int m = 32; m >= 1; m >>= 1) v += __shfl_xor(v, m, 64);
  return v;
}
__device__ __forceinline__ float wave_max64(float v) {
  #pragma unroll
  for (int m = 32; m >= 1; m >>= 1) v = fmaxf(v, __shfl_xor(v, m, 64));
  return v;
}
__device__ __forceinline__ unsigned short bf16rne(float x) {
  unsigned u = __float_as_uint(x);
  return (unsigned short)((u + 0x7FFFu + ((u >> 16) & 1u)) >> 16);
}

// ---- pre: tile W into A-fragment bf16 layout + Wa = (W @ a) * log2e ----
__global__ __launch_bounds__(256) void pre_kernel(
    const float* __restrict__ Wf, const float* __restrict__ We,
    const float* __restrict__ a_fe, const float* __restrict__ a_ef,
    __hip_bfloat16* __restrict__ Wfrag, float* __restrict__ Wa)
{
  const int lane = threadIdx.x & 63, wid = threadIdx.x >> 6;
  const int dir = blockIdx.x >> 2, h = blockIdx.x & 3;
  const int cl = lane & 15, kq = lane >> 4;
  const float* W = (dir ? We : Wf) + (size_t)h * FD_ * HD_;
  __hip_bfloat16* fb = Wfrag + (size_t)(dir * 4 + h) * 8192;
  #pragma unroll
  for (int db = 0; db < 4; ++db) {
    unsigned short u[8];
    #pragma unroll
    for (int j = 0; j < 8; ++j)
      u[j] = bf16rne(W[(wid * 32 + kq * 8 + j) * HD_ + db * 16 + cl]);
    uint4 pk;
    pk.x = u[0] | ((unsigned)u[1] << 16);
    pk.y = u[2] | ((unsigned)u[3] << 16);
    pk.z = u[4] | ((unsigned)u[5] << 16);
    pk.w = u[6] | ((unsigned)u[7] << 16);
    *(uint4*)(fb + ((size_t)(wid * 4 + db) * 64 + lane) * 8) = pk;
  }
  if (wid == 0) {
    const float* a1 = a_fe + h * HD_;
    const float* a2 = a_ef + h * HD_;
    float* wa = Wa + (size_t)(dir * 4 + h) * 256;
    #pragma unroll
    for (int rep = 0; rep < 2; ++rep) {
      const int f = lane + rep * 64;
      const float* wr = W + (size_t)f * HD_;
      float s1 = 0.f, s2 = 0.f;
      #pragma unroll 8
      for (int d = 0; d < HD_; ++d) {
        s1 = fmaf(wr[d], a1[d], s1);
        s2 = fmaf(wr[d], a2[d], s2);
      }
      wa[f] = s1 * LOG2E;
      wa[128 + f] = s2 * LOG2E;
    }
  }
}

// ---- MFMA proj: 16 rows/wave; fragment-tiled V + row float2 + packed col u32 ----
template<int SWAP, int NN>
__device__ __forceinline__ void proj_mfma(
    const float* __restrict__ X0, const __hip_bfloat16* __restrict__ Wfrag,
    const float* __restrict__ Wa, __hip_bfloat16* __restrict__ Vp,
    float2* __restrict__ rowO, unsigned* __restrict__ colO,
    int job, float* __restrict__ ldsX)
{
  const int lane = threadIdx.x & 63;
  const int cl = lane & 15, kq = lane >> 4;
  const int nj = NN >> 4;
  const int nt = job & (nj - 1);
  const int bh = job / nj;
  const int n0 = nt * 16;
  const int h = bh & 3, b = bh >> 2;
  const float* x0 = X0 + ((size_t)b * NN + n0 + cl) * FD_ + kq * 8;
  const __hip_bfloat16* fb = Wfrag + (size_t)((SWAP ? 4 : 0) + h) * 8192;
  const float* wa = Wa + (size_t)((SWAP ? 4 : 0) + h) * 256 + kq * 8;

  bf16x8 wf[4][4];
  #pragma unroll
  for (int ks = 0; ks < 4; ++ks)
    #pragma unroll
    for (int db = 0; db < 4; ++db)
      wf[ks][db] = *(const bf16x8*)(fb + ((size_t)(ks * 4 + db) * 64 + lane) * 8);

  bf16x8 xf[4];
  float d1 = 0.f, d2 = 0.f;
  #pragma unroll
  for (int ks = 0; ks < 4; ++ks) {
    const f32x4 xa = *(const f32x4*)(x0 + ks * 32);
    const f32x4 xb = *(const f32x4*)(x0 + ks * 32 + 4);
    const f32x4 w1a = *(const f32x4*)(wa + ks * 32);
    const f32x4 w1b = *(const f32x4*)(wa + ks * 32 + 4);
    const f32x4 w2a = *(const f32x4*)(wa + 128 + ks * 32);
    const f32x4 w2b = *(const f32x4*)(wa + 128 + ks * 32 + 4);
    #pragma unroll
    for (int i = 0; i < 4; ++i) {
      d1 = fmaf(xa[i], w1a[i], fmaf(xb[i], w1b[i], d1));
      d2 = fmaf(xa[i], w2a[i], fmaf(xb[i], w2b[i], d2));
    }
    #pragma unroll
    for (int i = 0; i < 4; ++i) {
      xf[ks][i]     = (short)bf16rne(xa[i]);
      xf[ks][i + 4] = (short)bf16rne(xb[i]);
    }
  }
  d1 += __shfl_xor(d1, 16, 64); d1 += __shfl_xor(d1, 32, 64);
  d2 += __shfl_xor(d2, 16, 64); d2 += __shfl_xor(d2, 32, 64);

  f32x4 acc[4] = {};
  #pragma unroll
  for (int ks = 0; ks < 4; ++ks)
    #pragma unroll
    for (int db = 0; db < 4; ++db)
      acc[db] = __builtin_amdgcn_mfma_f32_16x16x32_bf16(wf[ks][db], xf[ks],
                                                        acc[db], 0, 0, 0);
  #pragma unroll
  for (int db = 0; db < 4; ++db)
    *(f32x4*)(ldsX + cl * 68 + db * 16 + kq * 4) = acc[db];
  const int mt = n0 >> 6;
  #pragma unroll
  for (int c = 0; c < 2; ++c) {
    const int nb = n0 + c * 8;
    const int ks2 = (nb >> 5) & 1, q2 = (nb >> 3) & 3;
    unsigned short u[8];
    #pragma unroll
    for (int j = 0; j < 8; ++j)
      u[j] = bf16rne(ldsX[(c * 8 + j) * 68 + lane]);
    uint4 pk;
    pk.x = u[0] | ((unsigned)u[1] << 16);
    pk.y = u[2] | ((unsigned)u[3] << 16);
    pk.z = u[4] | ((unsigned)u[5] << 16);
    pk.w = u[6] | ((unsigned)u[7] << 16);
    *(uint4*)(Vp + ((size_t)((mt * 8 + ks2 * 4 + (lane >> 4)) * 64
                             + q2 * 16 + (lane & 15))) * 8) = pk;
  }
  if (kq == 0) {
    const float rd = SWAP ? d2 : d1;
    const float cd = SWAP ? d1 : d2;
    float2 rp;
    rp.x = exp2f(rd - KH);
    rp.y = exp2f(0.2f * rd - KH);
    const size_t idxn = (size_t)bh * NN + n0 + cl;
    rowO[idxn] = rp;
    colO[idxn] = (unsigned)bf16rne(exp2f(cd - KH)) |
                 ((unsigned)bf16rne(exp2f(0.2f * cd - KH)) << 16);
  }
}

// ---- bitpack: transposed bits_t[mt][n] ----
__device__ __forceinline__ void bitpack_body(
    const int* __restrict__ adj_fe, const int* __restrict__ adj_ef,
    u64* __restrict__ btfe, u64* __restrict__ btef, int id)
{
  const int lane = threadIdx.x & 63;
  const int* adj; u64* bt; int N, M, mt, g;
  if (id < 8192) {                            // fe: 64 mt x 128 g
    adj = adj_fe; bt = btfe; N = NF_; M = NE_;
    mt = id >> 7; g = id & 127;
  } else {                                    // ef: 32 mt x 256 g
    const int k = id - 8192;
    adj = adj_ef; bt = btef; N = NE_; M = NF_;
    mt = k >> 8; g = k & 255;
  }
  const int* base = adj + (size_t)(g * 16) * M + mt * 64 + lane;
  int v[16];
  #pragma unroll
  for (int r = 0; r < 16; ++r) v[r] = base[(size_t)r * M];
  u64 mine = 0;
  #pragma unroll
  for (int r = 0; r < 16; ++r) {
    u64 msk = __ballot(v[r] != 0);
    if (lane == r) mine = msk;
  }
  if (lane < 16) bt[(size_t)mt * N + g * 16 + lane] = mine;
}

// ---- fused prep ----
__global__ __launch_bounds__(256) void prep_kernel(
    const float* __restrict__ F0, const float* __restrict__ E0,
    const int* __restrict__ adj_fe, const int* __restrict__ adj_ef,
    const __hip_bfloat16* __restrict__ Wfrag, const float* __restrict__ Wa,
    __hip_bfloat16* __restrict__ Ftl, __hip_bfloat16* __restrict__ Etl,
    float2* __restrict__ rowF, unsigned* __restrict__ colF,
    float2* __restrict__ rowE, unsigned* __restrict__ colE,
    u64* __restrict__ btfe, u64* __restrict__ btef)
{
  __shared__ __align__(16) float ldsX[4][16 * 68];
  const int blk = blockIdx.x;
  const int wid = threadIdx.x >> 6;
  if (blk < 4096) {
    bitpack_body(adj_fe, adj_ef, btfe, btef, blk * 4 + wid);
  } else {
    const int job = (blk - 4096) * 4 + wid;   // [0, 3072)
    if (job < 1024) {
      const int bh = job >> 7;
      proj_mfma<0, NF_>(F0, Wfrag, Wa, Ftl + (size_t)bh * 32 * 4096,
                        rowF, colF, job, ldsX[wid]);
    } else {
      const int j2 = job - 1024;
      const int bh = j2 >> 8;
      proj_mfma<1, NE_>(E0, Wfrag, Wa, Etl + (size_t)bh * 64 * 4096,
                        rowE, colE, j2, ldsX[wid]);
    }
  }
}

// ---- attention inner loop: 1 fragment, DOUBLE-BUFFERED tile operands.
// All buffer elements are macro-NAMED scalars (no arrays/lambdas). The
// next tile's 13 loads issue one full tile of work ahead (R7's schedule:
// kernel is load-latency-bound — R12 falsified VALU-bound).
template<int TQ, int NN>
__device__ __forceinline__ void attn_wave(
    const __hip_bfloat16* __restrict__ vpp, const unsigned* __restrict__ colp,
    const u64* __restrict__ bt, float Ea, float Ga,
    int n0, int mt0, int cl, int kq,
    f32x4 (&accT)[4], f32x4 &accS)
{
  const int lane = threadIdx.x & 63;
  bf16x8 ones;
  #pragma unroll
  for (int i = 0; i < 8; ++i) ones[i] = (short)0x3F80;  // bf16 1.0

  const __hip_bfloat16* tb = vpp + (size_t)mt0 * 4096 + (size_t)lane * 8;
  const unsigned* cp = colp + mt0 * 64 + kq * 8;
  const u64* bp = bt + (size_t)mt0 * NN + n0 + cl;
  const int shk = kq * 8;

  bf16x8 vf0A, vf1A, vf2A, vf3A, vf4A, vf5A, vf6A, vf7A;
  bf16x8 vf0B, vf1B, vf2B, vf3B, vf4B, vf5B, vf6B, vf7B;
  uint32x4 cc0A, cc1A, cc2A, cc3A, cc0B, cc1B, cc2B, cc3B;
  u64 sA, sB;

#define LOADT(S) {                                                        \
    vf0##S = *(const bf16x8*)(tb);                                        \
    vf1##S = *(const bf16x8*)(tb + 512);                                  \
    vf2##S = *(const bf16x8*)(tb + 1024);                                 \
    vf3##S = *(const bf16x8*)(tb + 1536);                                 \
    vf4##S = *(const bf16x8*)(tb + 2048);                                 \
    vf5##S = *(const bf16x8*)(tb + 2560);                                 \
    vf6##S = *(const bf16x8*)(tb + 3072);                                 \
    vf7##S = *(const bf16x8*)(tb + 3584);                                 \
    cc0##S = *(const uint32x4*)(cp);                                      \
    cc1##S = *(const uint32x4*)(cp + 4);                                  \
    cc2##S = *(const uint32x4*)(cp + 32);                                 \
    cc3##S = *(const uint32x4*)(cp + 36);                                 \
    s##S = (*bp) >> shk;                                                  \
    tb += 4096; cp += 64; bp += NN;                                       \
  }

#define PJ(CC, JB, J) {                                                   \
      const unsigned cv = (CC)[J];                                        \
      const float Eb = __uint_as_float(cv << 16);                         \
      const float Gb = __uint_as_float(cv & 0xffff0000u);                 \
      float e = fmaxf(Ea * Eb, Ga * Gb);       /* exp2(lrelu(s')-C2) */   \
      const int sm = ((int)(mw << (31 - (JB + J)))) >> 31;                \
      e = __int_as_float(__float_as_int(e) & sm);                         \
      __hip_bfloat16 hb = __float2bfloat16(e);                            \
      pf[JB + J] = *(const short*)&hb;                                    \
    }

#define COMPT(S) {                                                        \
    bf16x8 pf;                                                            \
    unsigned mw = (unsigned)s##S;                                         \
    PJ(cc0##S, 0, 0) PJ(cc0##S, 0, 1) PJ(cc0##S, 0, 2) PJ(cc0##S, 0, 3)   \
    PJ(cc1##S, 4, 0) PJ(cc1##S, 4, 1) PJ(cc1##S, 4, 2) PJ(cc1##S, 4, 3)   \
    accS = __builtin_amdgcn_mfma_f32_16x16x32_bf16(pf, ones, accS, 0, 0, 0); \
    accT[0] = __builtin_amdgcn_mfma_f32_16x16x32_bf16(pf, vf0##S, accT[0], 0, 0, 0); \
    accT[1] = __builtin_amdgcn_mfma_f32_16x16x32_bf16(pf, vf1##S, accT[1], 0, 0, 0); \
    accT[2] = __builtin_amdgcn_mfma_f32_16x16x32_bf16(pf, vf2##S, accT[2], 0, 0, 0); \
    accT[3] = __builtin_amdgcn_mfma_f32_16x16x32_bf16(pf, vf3##S, accT[3], 0, 0, 0); \
    mw = (unsigned)(s##S >> 32);                                          \
    PJ(cc2##S, 0, 0) PJ(cc2##S, 0, 1) PJ(cc2##S, 0, 2) PJ(cc2##S, 0, 3)   \
    PJ(cc3##S, 4, 0) PJ(cc3##S, 4, 1) PJ(cc3##S, 4, 2) PJ(cc3##S, 4, 3)   \
    accS = __builtin_amdgcn_mfma_f32_16x16x32_bf16(pf, ones, accS, 0, 0, 0); \
    accT[0] = __builtin_amdgcn_mfma_f32_16x16x32_bf16(pf, vf4##S, accT[0], 0, 0, 0); \
    accT[1] = __builtin_amdgcn_mfma_f32_16x16x32_bf16(pf, vf5##S, accT[1], 0, 0, 0); \
    accT[2] = __builtin_amdgcn_mfma_f32_16x16x32_bf16(pf, vf6##S, accT[2], 0, 0, 0); \
    accT[3] = __builtin_amdgcn_mfma_f32_16x16x32_bf16(pf, vf7##S, accT[3], 0, 0, 0); \
  }

  LOADT(A)
  #pragma unroll 1
  for (int t = 0; t < TQ; t += 2) {
    LOADT(B)
    COMPT(A)
    if (t + 2 < TQ) LOADT(A)
    COMPT(B)
  }
#undef LOADT
#undef PJ
#undef COMPT
}

// ---- fused attention: block = 16 rows, 4 waves split M; XCD-local bh ----
__global__ __launch_bounds__(256, 3) void attn_kernel(
    const __hip_bfloat16* __restrict__ Ftl, const __hip_bfloat16* __restrict__ Etl,
    const float2* __restrict__ rowF, const unsigned* __restrict__ colF,
    const float2* __restrict__ rowE, const unsigned* __restrict__ colE,
    const u64* __restrict__ btfe, const u64* __restrict__ btef,
    float* __restrict__ out)
{
  __shared__ __align__(16) float ldsO[4 * 4 * 64 * 4];  // 16KB
  __shared__ float ldsS[4 * 16];

  const int lane = threadIdx.x & 63;
  const int wid  = threadIdx.x >> 6;
  const int cl = lane & 15, kq = lane >> 4;
  const int blk = blockIdx.x;

  int N, bh, n0;
  float* obase;
  bool relu;
  f32x4 accT[4] = {};
  f32x4 accS = {0.f, 0.f, 0.f, 0.f};

  if (blk < 1024) {            // fe
    bh = blk & 7;
    n0 = (blk >> 3) * 16;
    N = NF_;
    const float2 rp = rowF[(size_t)bh * NF_ + n0 + cl];
    attn_wave<16, NF_>(Etl + (size_t)bh * 64 * 4096, colE + (size_t)bh * NE_,
                       btfe, rp.x, rp.y, n0, wid * 16, cl, kq, accT, accS);
    obase = out; relu = false;
  } else {                     // ef
    const int k2 = blk - 1024;
    bh = k2 & 7;
    n0 = (k2 >> 3) * 16;
    N = NE_;
    const float2 rp = rowE[(size_t)bh * NE_ + n0 + cl];
    attn_wave<8, NE_>(Ftl + (size_t)bh * 32 * 4096, colF + (size_t)bh * NF_,
                      btef, rp.x, rp.y, n0, wid * 8, cl, kq, accT, accS);
    obase = out + (size_t)B_ * NF_ * 256; relu = true;
  }

  #pragma unroll
  for (int db = 0; db < 4; ++db)
    *(f32x4*)&ldsO[((db * 4 + wid) * 64 + lane) * 4] = accT[db];
  if (cl == 0) {
    #pragma unroll
    for (int reg = 0; reg < 4; ++reg)
      ldsS[wid * 16 + kq * 4 + reg] = accS[reg];
  }
  __syncthreads();

  f32x4 osum = {0.f, 0.f, 0.f, 0.f};
  #pragma unroll
  for (int s = 0; s < 4; ++s)
    osum += *(const f32x4*)&ldsO[((wid * 4 + s) * 64 + lane) * 4];
  float stot[4];
  #pragma unroll
  for (int reg = 0; reg < 4; ++reg) {
    stot[reg] = 0.f;
    #pragma unroll
    for (int s = 0; s < 4; ++s) stot[reg] += ldsS[s * 16 + kq * 4 + reg];
  }
  const int b = bh >> 2, h = bh & 3;
  float* orow = obase + ((size_t)b * N + n0 + kq * 4) * 256 + h * HD_ + wid * 16 + cl;
  #pragma unroll
  for (int reg = 0; reg < 4; ++reg) {
    float v = osum[reg] / stot[reg];
    if (relu) v = fmaxf(v, 0.0f);
    orow[reg * 256] = v;
  }
}

// in-place softmax over the 256-channel axis
__global__ __launch_bounds__(256) void softmax256_kernel(float* __restrict__ io)
{
  const int t = threadIdx.x;
  const int lane = t & 63, wid = t >> 6;
  float v = io[(long)blockIdx.x * 256 + t];
  __shared__ float red[8];
  float m = wave_max64(v);
  if (lane == 0) red[wid] = m;
  __syncthreads();
  m = fmaxf(fmaxf(red[0], red[1]), fmaxf(red[2], red[3]));
  float e = __expf(v - m);
  float s = wave_sum64(e);
  if (lane == 0) red[4 + wid] = s;
  __syncthreads();
  s = (red[4] + red[5]) + (red[6] + red[7]);
  io[(long)blockIdx.x * 256 + t] = e / s;
}

extern "C" void kernel_launch(void* const* d_in, const int* in_sizes, int n_in,
                              void* d_out, int out_size, void* d_ws, size_t ws_size,
                              hipStream_t stream)
{
  const float* F0   = (const float*)d_in[0];
  const float* E0   = (const float*)d_in[1];
  const int* adj_fe = (const int*)d_in[2];
  const int* adj_ef = (const int*)d_in[3];
  const float* Wf   = (const float*)d_in[4];
  const float* We   = (const float*)d_in[5];
  const float* a_fe = (const float*)d_in[6];
  const float* a_ef = (const float*)d_in[7];
  float* out = (float*)d_out;

  char* ws = (char*)d_ws;
  float2* rowF = (float2*)ws;                               // 128KB
  float2* rowE = (float2*)(ws + (128 << 10));               // 256KB
  unsigned* colF = (unsigned*)(ws + (384 << 10));           // 64KB
  unsigned* colE = (unsigned*)(ws + (448 << 10));           // 128KB
  u64* btfe = (u64*)(ws + (576 << 10));                     // 1MB
  u64* btef = btfe + (size_t)NF_ * (NE_ / 64);              // 1MB
  __hip_bfloat16* Ftl = (__hip_bfloat16*)(btef + (size_t)NE_ * (NF_ / 64)); // 2MB
  __hip_bfloat16* Etl = Ftl + (size_t)8 * 32 * 4096;        // 4MB
  __hip_bfloat16* Wfrag = Etl + (size_t)8 * 64 * 4096;
  float* Wa = (float*)(Wfrag + (size_t)8 * 8192);

  pre_kernel<<<8, 256, 0, stream>>>(Wf, We, a_fe, a_ef, Wfrag, Wa);
  prep_kernel<<<4864, 256, 0, stream>>>(F0, E0, adj_fe, adj_ef, Wfrag, Wa,
                                        Ftl, Etl, rowF, colF, rowE, colE,
                                        btfe, btef);
  attn_kernel<<<3072, 256, 0, stream>>>(Ftl, Etl, rowF, colF, rowE, colE,
                                        btfe, btef, out);
  softmax256_kernel<<<B_ * NF_, 256, 0, stream>>>(out);
}